// Round 1
// baseline (143.587 us; speedup 1.0000x reference)
//
#include <hip/hip_runtime.h>

#define NPTS 262144
#define NCLS 20
#define KNBR 16
#define IGNORE_INDEX (-1)

// -------- kernel 1: row softmax (float32, 20 classes) + zero accumulators ----
__global__ __launch_bounds__(256) void softmax_kernel(
    const float* __restrict__ logits, float* __restrict__ probs,
    double* __restrict__ sum_acc, unsigned int* __restrict__ cnt_acc, int n) {
    int i = blockIdx.x * blockDim.x + threadIdx.x;
    if (i == 0) { *sum_acc = 0.0; *cnt_acc = 0u; }
    if (i >= n) return;

    const float4* r4 = (const float4*)(logits + (size_t)i * NCLS);
    float v[NCLS];
#pragma unroll
    for (int q = 0; q < 5; ++q) {
        float4 t = r4[q];
        v[4 * q + 0] = t.x; v[4 * q + 1] = t.y;
        v[4 * q + 2] = t.z; v[4 * q + 3] = t.w;
    }
    float m = v[0];
#pragma unroll
    for (int c = 1; c < NCLS; ++c) m = fmaxf(m, v[c]);
    float s = 0.f;
#pragma unroll
    for (int c = 0; c < NCLS; ++c) { v[c] = __expf(v[c] - m); s += v[c]; }
    float inv = 1.0f / s;
    float4* o4 = (float4*)(probs + (size_t)i * NCLS);
#pragma unroll
    for (int q = 0; q < 5; ++q) {
        o4[q] = make_float4(v[4 * q + 0] * inv, v[4 * q + 1] * inv,
                            v[4 * q + 2] * inv, v[4 * q + 3] * inv);
    }
}

// -------- kernel 2: masked pairwise distance sum ----------------------------
__global__ __launch_bounds__(256) void loss_kernel(
    const float* __restrict__ probs, const int* __restrict__ labels,
    const int* __restrict__ ref_idx,
    double* __restrict__ sum_acc, unsigned int* __restrict__ cnt_acc, int n) {
    int i = blockIdx.x * blockDim.x + threadIdx.x;
    double dsum = 0.0;
    unsigned int cnt = 0;

    if (i < n) {
        int li = labels[i];
        if (li != IGNORE_INDEX) {
            float p[NCLS];
            const float4* p4 = (const float4*)(probs + (size_t)i * NCLS);
#pragma unroll
            for (int q = 0; q < 5; ++q) {
                float4 t = p4[q];
                p[4 * q + 0] = t.x; p[4 * q + 1] = t.y;
                p[4 * q + 2] = t.z; p[4 * q + 3] = t.w;
            }
            const int* ridx = ref_idx + (size_t)i * KNBR;
#pragma unroll
            for (int j = 0; j < KNBR; ++j) {
                int r = ridx[j];
                if (r < 0) continue;                 // knn_mask
                int nl = labels[r];
                if (nl == IGNORE_INDEX || nl != li) continue;  // valid + same-label
                const float4* q4 = (const float4*)(probs + (size_t)r * NCLS);
                float d = 0.f;
#pragma unroll
                for (int q = 0; q < 5; ++q) {
                    float4 t = q4[q];
                    float dx = p[4 * q + 0] - t.x; d = fmaf(dx, dx, d);
                    float dy = p[4 * q + 1] - t.y; d = fmaf(dy, dy, d);
                    float dz = p[4 * q + 2] - t.z; d = fmaf(dz, dz, d);
                    float dw = p[4 * q + 3] - t.w; d = fmaf(dw, dw, d);
                }
                dsum += (double)d;
                cnt += 1u;
            }
        }
    }

    // wave64 shuffle reduce
#pragma unroll
    for (int off = 32; off > 0; off >>= 1) {
        dsum += __shfl_down(dsum, off, 64);
        cnt  += __shfl_down(cnt,  off, 64);
    }
    __shared__ double s_sum[4];
    __shared__ unsigned int s_cnt[4];
    int wave = threadIdx.x >> 6;
    int lane = threadIdx.x & 63;
    if (lane == 0) { s_sum[wave] = dsum; s_cnt[wave] = cnt; }
    __syncthreads();
    if (threadIdx.x == 0) {
        double bs = s_sum[0] + s_sum[1] + s_sum[2] + s_sum[3];
        unsigned int bc = s_cnt[0] + s_cnt[1] + s_cnt[2] + s_cnt[3];
        atomicAdd(sum_acc, bs);
        atomicAdd(cnt_acc, bc);
    }
}

// -------- kernel 3: finalize ------------------------------------------------
__global__ void finalize_kernel(const double* __restrict__ sum_acc,
                                const unsigned int* __restrict__ cnt_acc,
                                float* __restrict__ out) {
    double s = *sum_acc;
    double c = (double)max(*cnt_acc, 1u);
    out[0] = (float)(s / c);   // LOSS_WEIGHT = 1.0
}

extern "C" void kernel_launch(void* const* d_in, const int* in_sizes, int n_in,
                              void* d_out, int out_size, void* d_ws, size_t ws_size,
                              hipStream_t stream) {
    const float* seg_logits = (const float*)d_in[0];
    // d_in[1] = coord — unused (KNN indices are given)
    const int* labels   = (const int*)d_in[2];
    const int* ref_idx  = (const int*)d_in[3];
    float* out = (float*)d_out;
    const int n = in_sizes[2];                     // 262144

    float* probs = (float*)d_ws;                   // n*20 floats = 20.97 MB
    char* acc_base = (char*)d_ws + (size_t)n * NCLS * sizeof(float);
    double* sum_acc = (double*)acc_base;           // 8B-aligned (n*80 % 8 == 0)
    unsigned int* cnt_acc = (unsigned int*)(acc_base + sizeof(double));

    int blocks = (n + 255) / 256;
    softmax_kernel<<<blocks, 256, 0, stream>>>(seg_logits, probs, sum_acc, cnt_acc, n);
    loss_kernel<<<blocks, 256, 0, stream>>>(probs, labels, ref_idx, sum_acc, cnt_acc, n);
    finalize_kernel<<<1, 1, 0, stream>>>(sum_acc, cnt_acc, out);
}